// Round 2
// baseline (711.498 us; speedup 1.0000x reference)
//
#include <hip/hip_runtime.h>
#include <hip/hip_cooperative_groups.h>
#include <math.h>

namespace cg = cooperative_groups;

#define BB 256
#define PP 16
#define LL 4
#define EE 128
#define NPATH (BB*PP)     // 4096
#define NMOD 512
#define CC1 512
#define CC2 256

// ---------------- workspace layout (fast path) ----------------
#define WS_STATE   0                              // [4096][2][128] f32 = 4 MB
#define WS_CNT     (NPATH*2*EE*4)                 // [4][512] int
#define WS_OFF     (WS_CNT  + LL*NMOD*4)          // [4][512] int
#define WS_LISTS   (WS_OFF  + LL*NMOD*4)          // [4][4096] int
#define WS_END     (WS_LISTS + LL*NPATH*4)        // ~4.08 MB

#define FMA4(A, S, Wv) do{ (A).x=fmaf((S),(Wv).x,(A).x); (A).y=fmaf((S),(Wv).y,(A).y); \
                           (A).z=fmaf((S),(Wv).z,(A).z); (A).w=fmaf((S),(Wv).w,(A).w);}while(0)

__device__ __forceinline__ unsigned short f2bf(float f) {
    unsigned u = __float_as_uint(f);
    u = (u + 0x7fffu + ((u >> 16) & 1u)) >> 16;   // round-to-nearest-even
    return (unsigned short)u;
}
__device__ __forceinline__ float bf2f(unsigned short s) {
    return __uint_as_float(((unsigned)s) << 16);
}

// ===========================================================================
// Fused cooperative kernel: bucket + seed + W-stage (once) + 4 steps + MLP.
// 512 blocks x 256 threads (2 blocks/CU). Block b owns module b's weights in
// LDS (bf16, [k][oc]) for ALL 4 steps -> W staged 1x instead of 4x, and no
// kernel-boundary drains between steps (grid.sync instead).
// ===========================================================================
__global__ __launch_bounds__(256, 2) void k_fused(
    const int* __restrict__ start_ids, const int* __restrict__ end_ids,
    const int* __restrict__ module_ids, const int* __restrict__ counts,
    const float* __restrict__ embed, const float* __restrict__ W,
    const float* __restrict__ bvec,
    const float* __restrict__ W1, const float* __restrict__ b1,
    const float* __restrict__ W2, const float* __restrict__ b2,
    const float* __restrict__ W3, const float* __restrict__ b3,
    float* __restrict__ out, float* __restrict__ state,
    int* __restrict__ cntg, int* __restrict__ offg, int* __restrict__ listsg)
{
    const int t   = threadIdx.x;
    const int blk = blockIdx.x;
    __shared__ unsigned short Ws[128*128];   // 32 KB, persists across steps
    __shared__ float vb[32*128];             // 16 KB, overlaid by bucket & MLP
    cg::grid_group grid = cg::this_grid();

    // ---------------- Phase A1: bucketing (blocks 0..3, one per step) ------
    if (blk < LL) {
        const int l = blk;
        int* s   = (int*)vb;        // [512] histogram
        int* pos = s + NMOD;        // [512] scatter cursors
        int* p   = pos + NMOD;      // [256] pair-sum scan
        s[t] = 0; s[t + 256] = 0;
        __syncthreads();
        int mloc[16];
        #pragma unroll
        for (int j = 0; j < 16; ++j) {
            const int bp = j*256 + t;
            const int m = module_ids[bp*LL + l];
            mloc[j] = m;
            atomicAdd(&s[m], 1);
        }
        __syncthreads();
        const int c0 = s[2*t], c1 = s[2*t+1];
        const int ps = c0 + c1;
        p[t] = ps;
        __syncthreads();
        for (int d = 1; d < 256; d <<= 1) {          // inclusive scan of pairs
            const int v = (t >= d) ? p[t-d] : 0;
            __syncthreads();
            p[t] += v;
            __syncthreads();
        }
        const int pe = p[t] - ps;                    // exclusive pair offset
        cntg[l*NMOD + 2*t]     = c0;
        cntg[l*NMOD + 2*t + 1] = c1;
        offg[l*NMOD + 2*t]     = pe;
        offg[l*NMOD + 2*t + 1] = pe + c0;
        pos[2*t]     = pe;
        pos[2*t + 1] = pe + c0;
        __syncthreads();
        #pragma unroll
        for (int j = 0; j < 16; ++j) {
            const int pp = atomicAdd(&pos[mloc[j]], 1);
            listsg[l*NPATH + pp] = j*256 + t;
        }
    }

    // ---------------- Phase A2: stage my module's W (ONCE) -----------------
    {
        const int oc = t & 127, kh = t >> 7;
        const float4* Wr = (const float4*)(W + ((size_t)blk*128 + oc)*128 + kh*64);
        #pragma unroll
        for (int it = 0; it < 16; ++it) {
            const float4 wv = Wr[it];
            const int k0 = kh*64 + it*4;
            Ws[(k0+0)*128 + oc] = f2bf(wv.x);
            Ws[(k0+1)*128 + oc] = f2bf(wv.y);
            Ws[(k0+2)*128 + oc] = f2bf(wv.z);
            Ws[(k0+3)*128 + oc] = f2bf(wv.w);
        }
    }

    // ---------------- Phase A3: seed 16 state rows per block ---------------
    {
        const int g = t >> 5, c4 = t & 31;
        #pragma unroll
        for (int rr = 0; rr < 2; ++rr) {
            const int row = blk*16 + g*2 + rr;       // 512*16 = 8192 rows
            const int bp  = row >> 1;
            const int id  = (row & 1) ? end_ids[bp] : start_ids[bp];
            ((float4*)state)[(size_t)row*32 + c4] =
                ((const float4*)(embed + (size_t)id*EE))[c4];
        }
    }

    grid.sync();

    // ---------------- 4 chain steps, W resident in LDS ---------------------
    const int cgi = t & 31;              // cols 4cgi..4cgi+3
    const int rg  = t >> 5;              // rows rg*4..rg*4+3
    const float4 bias4 = ((const float4*)(bvec + (size_t)blk*EE))[cgi];
    for (int l = 0; l < LL; ++l) {
        const int n = cntg[l*NMOD + blk];
        if (n > 0) {
            const int* lst = listsg + l*NPATH + offg[l*NMOD + blk];
            const int nr = 2*n;
            for (int base = 0; base < nr; base += 32) {
                __syncthreads();         // prior vb readers done
                #pragma unroll
                for (int it = 0; it < 4; ++it) {
                    const int flat = it*256 + t;
                    const int row = flat >> 5, c4 = flat & 31;
                    float4 v = make_float4(0.f, 0.f, 0.f, 0.f);
                    const int r = base + row;
                    if (r < nr) {
                        const int pv = lst[r >> 1]*2 + (r & 1);
                        v = ((const float4*)state)[(size_t)pv*32 + c4];
                    }
                    ((float4*)vb)[row*32 + c4] = v;
                }
                __syncthreads();

                float4 acc0 = make_float4(0,0,0,0), acc1 = make_float4(0,0,0,0);
                float4 acc2 = make_float4(0,0,0,0), acc3 = make_float4(0,0,0,0);
                const int r0 = rg*4;
                #pragma unroll 4
                for (int k0 = 0; k0 < 128; k0 += 4) {
                    const ushort4 u0 = *(const ushort4*)&Ws[(k0+0)*128 + 4*cgi];
                    const ushort4 u1 = *(const ushort4*)&Ws[(k0+1)*128 + 4*cgi];
                    const ushort4 u2 = *(const ushort4*)&Ws[(k0+2)*128 + 4*cgi];
                    const ushort4 u3 = *(const ushort4*)&Ws[(k0+3)*128 + 4*cgi];
                    const int q = k0 >> 2;
                    const float4 va0 = ((const float4*)vb)[(r0+0)*32 + q];
                    const float4 va1 = ((const float4*)vb)[(r0+1)*32 + q];
                    const float4 va2 = ((const float4*)vb)[(r0+2)*32 + q];
                    const float4 va3 = ((const float4*)vb)[(r0+3)*32 + q];
                    const float4 w0 = make_float4(bf2f(u0.x), bf2f(u0.y), bf2f(u0.z), bf2f(u0.w));
                    const float4 w1 = make_float4(bf2f(u1.x), bf2f(u1.y), bf2f(u1.z), bf2f(u1.w));
                    const float4 w2 = make_float4(bf2f(u2.x), bf2f(u2.y), bf2f(u2.z), bf2f(u2.w));
                    const float4 w3 = make_float4(bf2f(u3.x), bf2f(u3.y), bf2f(u3.z), bf2f(u3.w));
                    FMA4(acc0, va0.x, w0); FMA4(acc0, va0.y, w1); FMA4(acc0, va0.z, w2); FMA4(acc0, va0.w, w3);
                    FMA4(acc1, va1.x, w0); FMA4(acc1, va1.y, w1); FMA4(acc1, va1.z, w2); FMA4(acc1, va1.w, w3);
                    FMA4(acc2, va2.x, w0); FMA4(acc2, va2.y, w1); FMA4(acc2, va2.z, w2); FMA4(acc2, va2.w, w3);
                    FMA4(acc3, va3.x, w0); FMA4(acc3, va3.y, w1); FMA4(acc3, va3.z, w2); FMA4(acc3, va3.w, w3);
                }
                float4 accs[4] = {acc0, acc1, acc2, acc3};
                #pragma unroll
                for (int i = 0; i < 4; ++i) {
                    const int r = base + r0 + i;
                    if (r < nr) {
                        const int pv = lst[r >> 1]*2 + (r & 1);
                        float4 o = make_float4(accs[i].x + bias4.x, accs[i].y + bias4.y,
                                               accs[i].z + bias4.z, accs[i].w + bias4.w);
                        ((float4*)state)[(size_t)pv*32 + cgi] = o;
                    }
                }
            }
        }
        grid.sync();
    }

    // ---------------- MLP: blocks 0..127, 2 batch rows each ----------------
    if (blk < BB/2) {
        const int b0 = blk*2;
        float* pl  = vb;                    // [2][256]
        float* h1s = vb + 2*256;            // [2][512]
        float* h2s = vb + 2*256 + 2*CC1;    // [2][256]
        float* red = h2s + 2*CC2;           // [256]   (total 9216 B <= 16 KB)

        #pragma unroll
        for (int r = 0; r < 2; ++r) {
            const int b = b0 + r;
            float acc = 0.f, cs = 0.f;
            #pragma unroll
            for (int p = 0; p < PP; ++p) {
                const float cc = (float)counts[b*PP + p];
                cs += cc;
                acc = fmaf(cc, state[((size_t)(b*PP + p))*256 + t], acc);
            }
            pl[r*256 + t] = acc / cs;
        }
        __syncthreads();

        #pragma unroll
        for (int hh = 0; hh < 2; ++hh) {
            const int col = t + hh*256;
            const float4* w4 = (const float4*)(W1 + (size_t)col*256);
            float a0 = b1[col], a1 = a0;
            for (int q = 0; q < 64; ++q) {
                const float4 wv = w4[q];
                const float4 v0 = ((const float4*)pl)[q];
                const float4 v1 = ((const float4*)(pl + 256))[q];
                a0 = fmaf(wv.x,v0.x, fmaf(wv.y,v0.y, fmaf(wv.z,v0.z, fmaf(wv.w,v0.w, a0))));
                a1 = fmaf(wv.x,v1.x, fmaf(wv.y,v1.y, fmaf(wv.z,v1.z, fmaf(wv.w,v1.w, a1))));
            }
            h1s[col]       = fmaxf(a0, 0.f);
            h1s[CC1 + col] = fmaxf(a1, 0.f);
        }
        __syncthreads();

        {
            const float4* w4 = (const float4*)(W2 + (size_t)t*CC1);
            float a0 = b2[t], a1 = a0;
            for (int q = 0; q < 128; ++q) {
                const float4 wv = w4[q];
                const float4 v0 = ((const float4*)h1s)[q];
                const float4 v1 = ((const float4*)(h1s + CC1))[q];
                a0 = fmaf(wv.x,v0.x, fmaf(wv.y,v0.y, fmaf(wv.z,v0.z, fmaf(wv.w,v0.w, a0))));
                a1 = fmaf(wv.x,v1.x, fmaf(wv.y,v1.y, fmaf(wv.z,v1.z, fmaf(wv.w,v1.w, a1))));
            }
            h2s[t]       = fmaxf(a0, 0.f);
            h2s[CC2 + t] = fmaxf(a1, 0.f);
        }
        __syncthreads();

        {
            const int r = t >> 7, k = t & 127;
            red[t] = fmaf(W3[k], h2s[r*CC2 + k], W3[k+128] * h2s[r*CC2 + k + 128]);
            for (int sdx = 64; sdx > 0; sdx >>= 1) {
                __syncthreads();
                if ((t & 127) < sdx) red[t] += red[t + sdx];
            }
            __syncthreads();
            if ((t & 127) == 0)
                out[b0 + r] = 1.f / (1.f + expf(-(red[t] + b3[0])));
        }
    }
}

// ===========================================================================
// Proven multi-kernel pipeline kept as fallback (coop-launch failure / tiny ws)
// ===========================================================================
__global__ __launch_bounds__(512) void k_bucket(
    const int* __restrict__ module_ids, int* __restrict__ cnt_g,
    int* __restrict__ off_g, int* __restrict__ lists)
{
    const int l = blockIdx.x, t = threadIdx.x;
    __shared__ int s[NMOD];
    __shared__ int pos[NMOD];
    s[t] = 0;
    __syncthreads();
    int mloc[8];
    #pragma unroll
    for (int j = 0; j < 8; ++j) {
        const int bp = j*512 + t;
        const int m = module_ids[bp*LL + l];
        mloc[j] = m;
        atomicAdd(&s[m], 1);
    }
    __syncthreads();
    const int c = s[t];
    for (int d = 1; d < NMOD; d <<= 1) {
        const int v = (t >= d) ? s[t-d] : 0;
        __syncthreads();
        s[t] += v;
        __syncthreads();
    }
    const int excl = s[t] - c;
    cnt_g[l*NMOD + t] = c;
    off_g[l*NMOD + t] = excl;
    pos[t] = excl;
    __syncthreads();
    #pragma unroll
    for (int j = 0; j < 8; ++j) {
        const int p = atomicAdd(&pos[mloc[j]], 1);
        lists[l*NPATH + p] = j*512 + t;
    }
}

__global__ __launch_bounds__(256) void k_seed(
    const int* __restrict__ start_ids, const int* __restrict__ end_ids,
    const float* __restrict__ embed, float* __restrict__ state)
{
    const int bp = blockIdx.x, t = threadIdx.x;
    const int id = (t < EE) ? start_ids[bp] : end_ids[bp];
    state[(size_t)bp*256 + t] = embed[(size_t)id*EE + (t & (EE-1))];
}

__global__ __launch_bounds__(256) void k_step(
    const int l, const float* __restrict__ W, const float* __restrict__ bvec,
    const int* __restrict__ cnt, const int* __restrict__ off,
    const int* __restrict__ lists, float* __restrict__ state)
{
    __shared__ unsigned short Ws[128*128];
    __shared__ float vb[32*128];
    const int m = blockIdx.x, t = threadIdx.x;
    const int n = cnt[l*NMOD + m];
    if (n == 0) return;

    {
        const int oc = t & 127, kh = t >> 7;
        const float4* Wr = (const float4*)(W + ((size_t)m*128 + oc)*128 + kh*64);
        #pragma unroll
        for (int it = 0; it < 16; ++it) {
            const float4 wv = Wr[it];
            const int k0 = kh*64 + it*4;
            Ws[(k0+0)*128 + oc] = f2bf(wv.x);
            Ws[(k0+1)*128 + oc] = f2bf(wv.y);
            Ws[(k0+2)*128 + oc] = f2bf(wv.z);
            Ws[(k0+3)*128 + oc] = f2bf(wv.w);
        }
    }

    const int* lst = lists + l*NPATH + off[l*NMOD + m];
    const int nr = 2*n;
    const int cg = t & 31;
    const int rg = t >> 5;
    const float4 bias4 = ((const float4*)(bvec + (size_t)m*128))[cg];

    for (int base = 0; base < nr; base += 32) {
        __syncthreads();
        #pragma unroll
        for (int it = 0; it < 4; ++it) {
            const int flat = it*256 + t;
            const int row = flat >> 5, c4 = flat & 31;
            float4 v = make_float4(0.f, 0.f, 0.f, 0.f);
            const int r = base + row;
            if (r < nr) {
                const int pv = lst[r >> 1]*2 + (r & 1);
                v = ((const float4*)state)[pv*32 + c4];
            }
            ((float4*)vb)[row*32 + c4] = v;
        }
        __syncthreads();

        float4 acc0 = make_float4(0,0,0,0), acc1 = make_float4(0,0,0,0);
        float4 acc2 = make_float4(0,0,0,0), acc3 = make_float4(0,0,0,0);
        const int r0 = rg*4;
        #pragma unroll 4
        for (int k0 = 0; k0 < 128; k0 += 4) {
            const ushort4 u0 = *(const ushort4*)&Ws[(k0+0)*128 + 4*cg];
            const ushort4 u1 = *(const ushort4*)&Ws[(k0+1)*128 + 4*cg];
            const ushort4 u2 = *(const ushort4*)&Ws[(k0+2)*128 + 4*cg];
            const ushort4 u3 = *(const ushort4*)&Ws[(k0+3)*128 + 4*cg];
            const int q = k0 >> 2;
            const float4 va0 = ((const float4*)vb)[(r0+0)*32 + q];
            const float4 va1 = ((const float4*)vb)[(r0+1)*32 + q];
            const float4 va2 = ((const float4*)vb)[(r0+2)*32 + q];
            const float4 va3 = ((const float4*)vb)[(r0+3)*32 + q];
            const float4 w0 = make_float4(bf2f(u0.x), bf2f(u0.y), bf2f(u0.z), bf2f(u0.w));
            const float4 w1 = make_float4(bf2f(u1.x), bf2f(u1.y), bf2f(u1.z), bf2f(u1.w));
            const float4 w2 = make_float4(bf2f(u2.x), bf2f(u2.y), bf2f(u2.z), bf2f(u2.w));
            const float4 w3 = make_float4(bf2f(u3.x), bf2f(u3.y), bf2f(u3.z), bf2f(u3.w));
            FMA4(acc0, va0.x, w0); FMA4(acc0, va0.y, w1); FMA4(acc0, va0.z, w2); FMA4(acc0, va0.w, w3);
            FMA4(acc1, va1.x, w0); FMA4(acc1, va1.y, w1); FMA4(acc1, va1.z, w2); FMA4(acc1, va1.w, w3);
            FMA4(acc2, va2.x, w0); FMA4(acc2, va2.y, w1); FMA4(acc2, va2.z, w2); FMA4(acc2, va2.w, w3);
            FMA4(acc3, va3.x, w0); FMA4(acc3, va3.y, w1); FMA4(acc3, va3.z, w2); FMA4(acc3, va3.w, w3);
        }
        float4 accs[4] = {acc0, acc1, acc2, acc3};
        #pragma unroll
        for (int i = 0; i < 4; ++i) {
            const int r = base + r0 + i;
            if (r < nr) {
                const int pv = lst[r >> 1]*2 + (r & 1);
                float4 o = make_float4(accs[i].x + bias4.x, accs[i].y + bias4.y,
                                       accs[i].z + bias4.z, accs[i].w + bias4.w);
                ((float4*)state)[pv*32 + cg] = o;
            }
        }
    }
}

__global__ __launch_bounds__(256) void k_mlp(
    const int* __restrict__ counts, const float* __restrict__ state,
    const float* __restrict__ W1, const float* __restrict__ b1,
    const float* __restrict__ W2, const float* __restrict__ b2,
    const float* __restrict__ W3, const float* __restrict__ b3,
    float* __restrict__ out)
{
    const int t = threadIdx.x;
    const int b0 = blockIdx.x * 2;
    __shared__ float pl[2][256];
    __shared__ float h1s[2][CC1];
    __shared__ float h2s[2][CC2];
    __shared__ float red[256];

    #pragma unroll
    for (int r = 0; r < 2; ++r) {
        const int b = b0 + r;
        float acc = 0.f, cs = 0.f;
        #pragma unroll
        for (int p = 0; p < PP; ++p) {
            const float cc = (float)counts[b*PP + p];
            cs += cc;
            acc = fmaf(cc, state[((size_t)(b*PP + p))*256 + t], acc);
        }
        pl[r][t] = acc / cs;
    }
    __syncthreads();

    #pragma unroll
    for (int hh = 0; hh < 2; ++hh) {
        const int col = t + hh*256;
        const float4* w4 = (const float4*)(W1 + (size_t)col*256);
        float a0 = b1[col], a1 = a0;
        for (int q = 0; q < 64; ++q) {
            const float4 wv = w4[q];
            const float4 v0 = ((const float4*)pl[0])[q];
            const float4 v1 = ((const float4*)pl[1])[q];
            a0 = fmaf(wv.x,v0.x, fmaf(wv.y,v0.y, fmaf(wv.z,v0.z, fmaf(wv.w,v0.w, a0))));
            a1 = fmaf(wv.x,v1.x, fmaf(wv.y,v1.y, fmaf(wv.z,v1.z, fmaf(wv.w,v1.w, a1))));
        }
        h1s[0][col] = fmaxf(a0, 0.f);
        h1s[1][col] = fmaxf(a1, 0.f);
    }
    __syncthreads();

    {
        const float4* w4 = (const float4*)(W2 + (size_t)t*512);
        float a0 = b2[t], a1 = a0;
        for (int q = 0; q < 128; ++q) {
            const float4 wv = w4[q];
            const float4 v0 = ((const float4*)h1s[0])[q];
            const float4 v1 = ((const float4*)h1s[1])[q];
            a0 = fmaf(wv.x,v0.x, fmaf(wv.y,v0.y, fmaf(wv.z,v0.z, fmaf(wv.w,v0.w, a0))));
            a1 = fmaf(wv.x,v1.x, fmaf(wv.y,v1.y, fmaf(wv.z,v1.z, fmaf(wv.w,v1.w, a1))));
        }
        h2s[0][t] = fmaxf(a0, 0.f);
        h2s[1][t] = fmaxf(a1, 0.f);
    }
    __syncthreads();

    {
        const int r = t >> 7, k = t & 127;
        red[t] = fmaf(W3[k], h2s[r][k], W3[k+128] * h2s[r][k+128]);
        for (int s = 64; s > 0; s >>= 1) {
            __syncthreads();
            if ((t & 127) < s) red[t] += red[t + s];
        }
        __syncthreads();
        if ((t & 127) == 0)
            out[b0 + r] = 1.f / (1.f + expf(-(red[t] + b3[0])));
    }
}

__global__ __launch_bounds__(256) void fb_path_kernel(
    const int* __restrict__ start_ids, const int* __restrict__ end_ids,
    const int* __restrict__ module_ids,
    const float* __restrict__ embed, const float* __restrict__ W,
    const float* __restrict__ bvec, float* __restrict__ feat_ws)
{
    const int bp = blockIdx.x, t = threadIdx.x;
    __shared__ float bufx[2][EE];
    __shared__ float bufy[2][EE];
    const int sid = start_ids[bp], eid = end_ids[bp];
    if (t < EE) bufx[0][t]      = embed[(size_t)sid*EE + t];
    else        bufy[0][t - EE] = embed[(size_t)eid*EE + (t - EE)];
    __syncthreads();
    const int o = t & (EE - 1);
    int cur = 0;
    for (int l = 0; l < LL; ++l) {
        const int mid = module_ids[bp*LL + l];
        const float*  vin  = (t < EE) ? bufx[cur] : bufy[cur];
        const float4* v4   = (const float4*)vin;
        const float4* wrow = (const float4*)(W + ((size_t)mid*EE + o)*EE);
        float acc = bvec[(size_t)mid*EE + o];
        #pragma unroll 8
        for (int k = 0; k < EE/4; ++k) {
            const float4 wv = wrow[k]; const float4 v = v4[k];
            acc = fmaf(wv.x,v.x, fmaf(wv.y,v.y, fmaf(wv.z,v.z, fmaf(wv.w,v.w, acc))));
        }
        if (t < EE) bufx[1-cur][o] = acc; else bufy[1-cur][o] = acc;
        __syncthreads();
        cur = 1 - cur;
    }
    feat_ws[(size_t)bp*(2*EE) + t] = (t < EE) ? bufx[cur][t] : bufy[cur][t - EE];
}

__global__ __launch_bounds__(256) void fb_mlp_kernel(
    const int* __restrict__ counts, const float* __restrict__ feat_ws,
    const float* __restrict__ W1, const float* __restrict__ b1,
    const float* __restrict__ W2, const float* __restrict__ b2,
    const float* __restrict__ W3, const float* __restrict__ b3,
    float* __restrict__ out)
{
    const int t = threadIdx.x, b0 = blockIdx.x*8;
    __shared__ float pooled[8][2*EE];
    __shared__ float h1s[8][CC1];
    __shared__ float h2s[8][CC2];
    for (int j = 0; j < 8; ++j) {
        const int b = b0 + j;
        float acc = 0.f, csum = 0.f;
        #pragma unroll
        for (int p = 0; p < PP; ++p) {
            const float cc = (float)counts[b*PP + p];
            csum += cc;
            acc = fmaf(cc, feat_ws[(size_t)(b*PP + p)*(2*EE) + t], acc);
        }
        pooled[j][t] = acc / csum;
    }
    __syncthreads();
    for (int rh = 0; rh < 2; ++rh) {
        const int r = t + rh*256;
        float acc[8]; const float bb = b1[r];
        #pragma unroll
        for (int j = 0; j < 8; ++j) acc[j] = bb;
        const float4* w4 = (const float4*)(W1 + (size_t)r*(2*EE));
        for (int k = 0; k < (2*EE)/4; ++k) {
            const float4 wv = w4[k];
            #pragma unroll
            for (int j = 0; j < 8; ++j) {
                const float4 v = ((const float4*)pooled[j])[k];
                acc[j] = fmaf(wv.x,v.x, fmaf(wv.y,v.y, fmaf(wv.z,v.z, fmaf(wv.w,v.w, acc[j]))));
            }
        }
        #pragma unroll
        for (int j = 0; j < 8; ++j) h1s[j][r] = fmaxf(acc[j], 0.f);
    }
    __syncthreads();
    {
        const int r = t;
        float acc[8]; const float bb = b2[r];
        #pragma unroll
        for (int j = 0; j < 8; ++j) acc[j] = bb;
        const float4* w4 = (const float4*)(W2 + (size_t)r*CC1);
        for (int k = 0; k < CC1/4; ++k) {
            const float4 wv = w4[k];
            #pragma unroll
            for (int j = 0; j < 8; ++j) {
                const float4 v = ((const float4*)h1s[j])[k];
                acc[j] = fmaf(wv.x,v.x, fmaf(wv.y,v.y, fmaf(wv.z,v.z, fmaf(wv.w,v.w, acc[j]))));
            }
        }
        #pragma unroll
        for (int j = 0; j < 8; ++j) h2s[j][r] = fmaxf(acc[j], 0.f);
    }
    __syncthreads();
    const int j = t >> 5, k = t & 31;
    float partial = 0.f;
    #pragma unroll
    for (int m = 0; m < CC2; m += 32)
        partial = fmaf(W3[k + m], h2s[j][k + m], partial);
    #pragma unroll
    for (int s = 16; s >= 1; s >>= 1) partial += __shfl_down(partial, s, 32);
    if (k == 0) out[b0 + j] = 1.f / (1.f + expf(-(partial + b3[0])));
}

// ---------------------------------------------------------------------------
extern "C" void kernel_launch(void* const* d_in, const int* in_sizes, int n_in,
                              void* d_out, int out_size, void* d_ws, size_t ws_size,
                              hipStream_t stream)
{
    const int*   start_ids  = (const int*)d_in[0];
    const int*   end_ids    = (const int*)d_in[1];
    const int*   module_ids = (const int*)d_in[2];
    const int*   counts     = (const int*)d_in[3];
    const float* embed      = (const float*)d_in[4];
    const float* W          = (const float*)d_in[5];
    const float* bvec       = (const float*)d_in[6];
    const float* W1         = (const float*)d_in[7];
    const float* b1         = (const float*)d_in[8];
    const float* W2         = (const float*)d_in[9];
    const float* b2         = (const float*)d_in[10];
    const float* W3         = (const float*)d_in[11];
    const float* b3         = (const float*)d_in[12];
    float* out = (float*)d_out;
    char*  ws  = (char*)d_ws;

    if (ws_size >= (size_t)WS_END) {
        float* state = (float*)(ws + WS_STATE);
        int*   cnt   = (int*)(ws + WS_CNT);
        int*   offs  = (int*)(ws + WS_OFF);
        int*   lists = (int*)(ws + WS_LISTS);

        void* args[] = {
            (void*)&start_ids, (void*)&end_ids, (void*)&module_ids, (void*)&counts,
            (void*)&embed, (void*)&W, (void*)&bvec,
            (void*)&W1, (void*)&b1, (void*)&W2, (void*)&b2, (void*)&W3, (void*)&b3,
            (void*)&out, (void*)&state, (void*)&cnt, (void*)&offs, (void*)&lists};

        hipError_t e = hipLaunchCooperativeKernel(
            reinterpret_cast<const void*>(k_fused), dim3(NMOD), dim3(256),
            (void**)args, 0, stream);
        if (e == hipSuccess) return;

        // coop launch unavailable -> proven multi-kernel pipeline
        k_bucket<<<LL, 512, 0, stream>>>(module_ids, cnt, offs, lists);
        k_seed<<<NPATH, 256, 0, stream>>>(start_ids, end_ids, embed, state);
        for (int l = 0; l < LL; ++l)
            k_step<<<NMOD, 256, 0, stream>>>(l, W, bvec, cnt, offs, lists, state);
        k_mlp<<<BB/2, 256, 0, stream>>>(counts, state, W1, b1, W2, b2, W3, b3, out);
    } else {
        float* feat_ws = (float*)d_ws;
        fb_path_kernel<<<NPATH, 256, 0, stream>>>(start_ids, end_ids, module_ids,
                                                  embed, W, bvec, feat_ws);
        fb_mlp_kernel<<<BB/8, 256, 0, stream>>>(counts, feat_ws, W1, b1, W2, b2,
                                                W3, b3, out);
    }
}

// Round 3
// 452.378 us; speedup vs baseline: 1.5728x; 1.5728x over previous
//
#include <hip/hip_runtime.h>
#include <math.h>

#define BB 256
#define PP 16
#define LL 4
#define EE 128
#define NPATH (BB*PP)     // 4096
#define NMOD 512
#define CC1 512
#define CC2 256

// ---------------- workspace layout ----------------
// feat [4096][256] f32 = 4 MB at 0; Wbf [512][128][128] bf16 = 16 MB at 4 MB
#define WS_FEAT   0
#define WS_WBF    ((size_t)NPATH*2*EE*4)                  // 4 MB
#define WS_BF_END (WS_WBF + (size_t)NMOD*EE*EE*2)         // 20 MB

__device__ __forceinline__ unsigned short f2bf(float f) {
    unsigned u = __float_as_uint(f);
    u = (u + 0x7fffu + ((u >> 16) & 1u)) >> 16;   // round-to-nearest-even
    return (unsigned short)u;
}
__device__ __forceinline__ float bf2f(unsigned short s) {
    return __uint_as_float(((unsigned)s) << 16);
}

// ---------------- W -> bf16 conversion (one pass, 48 MB traffic) -----------
__global__ __launch_bounds__(256) void k_wconv(
    const float* __restrict__ W, unsigned short* __restrict__ Wbf)
{
    const size_t base = ((size_t)blockIdx.x*256 + threadIdx.x)*8;
    const float4 a = *(const float4*)(W + base);
    const float4 b = *(const float4*)(W + base + 4);
    uint4 u;
    u.x = (unsigned)f2bf(a.x) | ((unsigned)f2bf(a.y) << 16);
    u.y = (unsigned)f2bf(a.z) | ((unsigned)f2bf(a.w) << 16);
    u.z = (unsigned)f2bf(b.x) | ((unsigned)f2bf(b.y) << 16);
    u.w = (unsigned)f2bf(b.z) | ((unsigned)f2bf(b.w) << 16);
    *(uint4*)(Wbf + base) = u;
}

// ---------------- per-path chain: 2 paths/block, thread o owns element o ---
// x and y share the same W row -> one W read feeds two fma chains (the two
// independent chains also interleave to hide fma dep latency). State in LDS,
// broadcast reads (uniform address per wave -> conflict-free). 2048 blocks,
// tiny LDS/VGPR -> ~full wave residency (the bucketed design capped at 22%).
template<int USEBF>
__global__ __launch_bounds__(256) void k_chain(
    const int* __restrict__ start_ids, const int* __restrict__ end_ids,
    const int* __restrict__ module_ids, const float* __restrict__ embed,
    const float* __restrict__ W, const unsigned short* __restrict__ Wbf,
    const float* __restrict__ bvec, float* __restrict__ feat)
{
    const int t = threadIdx.x;
    const int p = t >> 7;            // which of the block's 2 paths
    const int o = t & 127;           // output element
    const int bp = blockIdx.x*2 + p;
    __shared__ float sx[2][2][EE];
    __shared__ float sy[2][2][EE];

    sx[p][0][o] = embed[(size_t)start_ids[bp]*EE + o];
    sy[p][0][o] = embed[(size_t)end_ids[bp]*EE + o];
    __syncthreads();

    int cur = 0;
    #pragma unroll
    for (int l = 0; l < LL; ++l) {
        const int mid = module_ids[bp*LL + l];
        float ax = bvec[(size_t)mid*EE + o];
        float ay = ax;
        if (USEBF) {
            const uint4* wr = (const uint4*)(Wbf + ((size_t)mid*EE + o)*EE);
            #pragma unroll
            for (int i = 0; i < EE; i += 8) {
                const uint4 wv = wr[i >> 3];
                const float4 xv0 = *(const float4*)&sx[p][cur][i];
                const float4 xv1 = *(const float4*)&sx[p][cur][i+4];
                const float4 yv0 = *(const float4*)&sy[p][cur][i];
                const float4 yv1 = *(const float4*)&sy[p][cur][i+4];
                const float w0 = bf2f((unsigned short)(wv.x & 0xffffu));
                const float w1 = bf2f((unsigned short)(wv.x >> 16));
                const float w2 = bf2f((unsigned short)(wv.y & 0xffffu));
                const float w3 = bf2f((unsigned short)(wv.y >> 16));
                const float w4 = bf2f((unsigned short)(wv.z & 0xffffu));
                const float w5 = bf2f((unsigned short)(wv.z >> 16));
                const float w6 = bf2f((unsigned short)(wv.w & 0xffffu));
                const float w7 = bf2f((unsigned short)(wv.w >> 16));
                ax = fmaf(w0, xv0.x, ax); ay = fmaf(w0, yv0.x, ay);
                ax = fmaf(w1, xv0.y, ax); ay = fmaf(w1, yv0.y, ay);
                ax = fmaf(w2, xv0.z, ax); ay = fmaf(w2, yv0.z, ay);
                ax = fmaf(w3, xv0.w, ax); ay = fmaf(w3, yv0.w, ay);
                ax = fmaf(w4, xv1.x, ax); ay = fmaf(w4, yv1.x, ay);
                ax = fmaf(w5, xv1.y, ax); ay = fmaf(w5, yv1.y, ay);
                ax = fmaf(w6, xv1.z, ax); ay = fmaf(w6, yv1.z, ay);
                ax = fmaf(w7, xv1.w, ax); ay = fmaf(w7, yv1.w, ay);
            }
        } else {
            const float4* wr = (const float4*)(W + ((size_t)mid*EE + o)*EE);
            #pragma unroll
            for (int i = 0; i < EE; i += 4) {
                const float4 wv = wr[i >> 2];
                const float4 xv = *(const float4*)&sx[p][cur][i];
                const float4 yv = *(const float4*)&sy[p][cur][i];
                ax = fmaf(wv.x, xv.x, ax); ay = fmaf(wv.x, yv.x, ay);
                ax = fmaf(wv.y, xv.y, ax); ay = fmaf(wv.y, yv.y, ay);
                ax = fmaf(wv.z, xv.z, ax); ay = fmaf(wv.z, yv.z, ay);
                ax = fmaf(wv.w, xv.w, ax); ay = fmaf(wv.w, yv.w, ay);
            }
        }
        sx[p][cur^1][o] = ax;
        sy[p][cur^1][o] = ay;
        __syncthreads();
        cur ^= 1;
    }

    feat[(size_t)bp*(2*EE) + o]      = sx[p][cur][o];
    feat[(size_t)bp*(2*EE) + EE + o] = sy[p][cur][o];
}

// ---------------- fused pooling + full MLP (proven, unchanged) -------------
__global__ __launch_bounds__(256) void k_mlp(
    const int* __restrict__ counts, const float* __restrict__ state,
    const float* __restrict__ W1, const float* __restrict__ b1,
    const float* __restrict__ W2, const float* __restrict__ b2,
    const float* __restrict__ W3, const float* __restrict__ b3,
    float* __restrict__ out)
{
    const int t = threadIdx.x;
    const int b0 = blockIdx.x * 2;
    __shared__ float pl[2][256];
    __shared__ float h1s[2][CC1];
    __shared__ float h2s[2][CC2];
    __shared__ float red[256];

    #pragma unroll
    for (int r = 0; r < 2; ++r) {
        const int b = b0 + r;
        float acc = 0.f, cs = 0.f;
        #pragma unroll
        for (int p = 0; p < PP; ++p) {
            const float cc = (float)counts[b*PP + p];
            cs += cc;
            acc = fmaf(cc, state[((size_t)(b*PP + p))*256 + t], acc);
        }
        pl[r][t] = acc / cs;
    }
    __syncthreads();

    #pragma unroll
    for (int hh = 0; hh < 2; ++hh) {
        const int col = t + hh*256;
        const float4* w4 = (const float4*)(W1 + (size_t)col*256);
        float a0 = b1[col], a1 = a0;
        for (int q = 0; q < 64; ++q) {
            const float4 wv = w4[q];
            const float4 v0 = ((const float4*)pl[0])[q];
            const float4 v1 = ((const float4*)pl[1])[q];
            a0 = fmaf(wv.x,v0.x, fmaf(wv.y,v0.y, fmaf(wv.z,v0.z, fmaf(wv.w,v0.w, a0))));
            a1 = fmaf(wv.x,v1.x, fmaf(wv.y,v1.y, fmaf(wv.z,v1.z, fmaf(wv.w,v1.w, a1))));
        }
        h1s[0][col] = fmaxf(a0, 0.f);
        h1s[1][col] = fmaxf(a1, 0.f);
    }
    __syncthreads();

    {
        const float4* w4 = (const float4*)(W2 + (size_t)t*512);
        float a0 = b2[t], a1 = a0;
        for (int q = 0; q < 128; ++q) {
            const float4 wv = w4[q];
            const float4 v0 = ((const float4*)h1s[0])[q];
            const float4 v1 = ((const float4*)h1s[1])[q];
            a0 = fmaf(wv.x,v0.x, fmaf(wv.y,v0.y, fmaf(wv.z,v0.z, fmaf(wv.w,v0.w, a0))));
            a1 = fmaf(wv.x,v1.x, fmaf(wv.y,v1.y, fmaf(wv.z,v1.z, fmaf(wv.w,v1.w, a1))));
        }
        h2s[0][t] = fmaxf(a0, 0.f);
        h2s[1][t] = fmaxf(a1, 0.f);
    }
    __syncthreads();

    {
        const int r = t >> 7, k = t & 127;
        red[t] = fmaf(W3[k], h2s[r][k], W3[k+128] * h2s[r][k+128]);
        for (int s = 64; s > 0; s >>= 1) {
            __syncthreads();
            if ((t & 127) < s) red[t] += red[t + s];
        }
        __syncthreads();
        if ((t & 127) == 0)
            out[b0 + r] = 1.f / (1.f + expf(-(red[t] + b3[0])));
    }
}

// ---------------------------------------------------------------------------
extern "C" void kernel_launch(void* const* d_in, const int* in_sizes, int n_in,
                              void* d_out, int out_size, void* d_ws, size_t ws_size,
                              hipStream_t stream)
{
    const int*   start_ids  = (const int*)d_in[0];
    const int*   end_ids    = (const int*)d_in[1];
    const int*   module_ids = (const int*)d_in[2];
    const int*   counts     = (const int*)d_in[3];
    const float* embed      = (const float*)d_in[4];
    const float* W          = (const float*)d_in[5];
    const float* bvec       = (const float*)d_in[6];
    const float* W1         = (const float*)d_in[7];
    const float* b1         = (const float*)d_in[8];
    const float* W2         = (const float*)d_in[9];
    const float* b2         = (const float*)d_in[10];
    const float* W3         = (const float*)d_in[11];
    const float* b3         = (const float*)d_in[12];
    float* out  = (float*)d_out;
    char*  ws   = (char*)d_ws;
    float* feat = (float*)(ws + WS_FEAT);

    if (ws_size >= WS_BF_END) {
        unsigned short* Wbf = (unsigned short*)(ws + WS_WBF);
        // 512*128*128 / (256*8) = 4096 blocks
        k_wconv<<<4096, 256, 0, stream>>>(W, Wbf);
        k_chain<1><<<NPATH/2, 256, 0, stream>>>(start_ids, end_ids, module_ids,
                                                embed, W, Wbf, bvec, feat);
    } else {
        k_chain<0><<<NPATH/2, 256, 0, stream>>>(start_ids, end_ids, module_ids,
                                                embed, W, (const unsigned short*)0,
                                                bvec, feat);
    }
    k_mlp<<<BB/2, 256, 0, stream>>>(counts, feat, W1, b1, W2, b2, W3, b3, out);
}

// Round 4
// 428.081 us; speedup vs baseline: 1.6621x; 1.0568x over previous
//
#include <hip/hip_runtime.h>
#include <math.h>

#define BB 256
#define PP 16
#define LL 4
#define EE 128
#define NPATH (BB*PP)     // 4096
#define NMOD 512
#define CC1 512
#define CC2 256

// ---------------- workspace layout ----------------
// feat [4096][256] f32 = 4 MB at 0; Wt [512][16][128][8] bf16 = 16 MB at 4 MB
#define WS_FEAT   0
#define WS_WT     ((size_t)NPATH*2*EE*4)                  // 4 MB
#define WS_END    (WS_WT + (size_t)NMOD*EE*EE*2)          // 20 MB

__device__ __forceinline__ unsigned short f2bf(float f) {
    unsigned u = __float_as_uint(f);
    u = (u + 0x7fffu + ((u >> 16) & 1u)) >> 16;   // round-to-nearest-even
    return (unsigned short)u;
}
__device__ __forceinline__ float bf2f(unsigned short s) {
    return __uint_as_float(((unsigned)s) << 16);
}

// ---------------- W -> bf16 transpose-convert ------------------------------
// Wt[mid][kc][o][j] bf16 with k = kc*8+j. Thread tid=(mid*16+kc)*128+o:
// reads W[mid][o][kc*8..+8] (32 B gather at 512 B stride, L2-absorbed, W read
// exactly once), writes uint4 at Wt+tid*8 -> consecutive lanes = consecutive
// 16 B -> fully coalesced stores. In k_chain, lane o loading chunk kc then
// reads Wt[(mid*16+kc)*128+o] -> 64 lanes = one contiguous 1 KB transaction
// (the round-3 layout was a 64-cache-line gather per instruction).
__global__ __launch_bounds__(256) void k_wtrans(
    const float* __restrict__ W, unsigned short* __restrict__ Wt)
{
    const int tid = blockIdx.x*256 + threadIdx.x;     // 512*16*128 threads
    const int o   = tid & 127;
    const int kc  = (tid >> 7) & 15;
    const int mid = tid >> 11;
    const float* src = W + ((size_t)mid*EE + o)*EE + kc*8;
    const float4 a = *(const float4*)(src);
    const float4 b = *(const float4*)(src + 4);
    uint4 u;
    u.x = (unsigned)f2bf(a.x) | ((unsigned)f2bf(a.y) << 16);
    u.y = (unsigned)f2bf(a.z) | ((unsigned)f2bf(a.w) << 16);
    u.z = (unsigned)f2bf(b.x) | ((unsigned)f2bf(b.y) << 16);
    u.w = (unsigned)f2bf(b.z) | ((unsigned)f2bf(b.w) << 16);
    *(uint4*)(Wt + (size_t)tid*8) = u;
}

// ---------------- per-path chain: 2 paths/block, thread o owns element o ---
// x and y share the same W read -> one coalesced uint4 feeds two independent
// fma chains (ILP). State in LDS, broadcast reads (wave-uniform address ->
// conflict-free). 2048 blocks, 4 KB LDS, VGPR capped at 128 by launch_bounds
// -> 16 waves/CU. Numeric order identical to the round-3 passing kernel.
template<int USEBF>
__global__ __launch_bounds__(256, 4) void k_chain(
    const int* __restrict__ start_ids, const int* __restrict__ end_ids,
    const int* __restrict__ module_ids, const float* __restrict__ embed,
    const float* __restrict__ W, const unsigned short* __restrict__ Wt,
    const float* __restrict__ bvec, float* __restrict__ feat)
{
    const int t = threadIdx.x;
    const int p = t >> 7;            // which of the block's 2 paths
    const int o = t & 127;           // output element
    const int bp = blockIdx.x*2 + p;
    __shared__ float sx[2][2][EE];
    __shared__ float sy[2][2][EE];

    sx[p][0][o] = embed[(size_t)start_ids[bp]*EE + o];
    sy[p][0][o] = embed[(size_t)end_ids[bp]*EE + o];
    __syncthreads();

    int cur = 0;
    for (int l = 0; l < LL; ++l) {
        const int mid = module_ids[bp*LL + l];
        float ax = bvec[(size_t)mid*EE + o];
        float ay = ax;
        if (USEBF) {
            const uint4*  wt  = (const uint4*)(Wt + (size_t)mid*16384); // [kc][o]
            const float4* xv4 = (const float4*)sx[p][cur];
            const float4* yv4 = (const float4*)sy[p][cur];
            #pragma unroll 8
            for (int kc = 0; kc < 16; ++kc) {
                const uint4 wv = wt[kc*128 + o];          // coalesced 1 KB/wave
                const float4 xv0 = xv4[kc*2],   yv0 = yv4[kc*2];
                const float4 xv1 = xv4[kc*2+1], yv1 = yv4[kc*2+1];
                const float w0 = bf2f((unsigned short)(wv.x & 0xffffu));
                const float w1 = bf2f((unsigned short)(wv.x >> 16));
                const float w2 = bf2f((unsigned short)(wv.y & 0xffffu));
                const float w3 = bf2f((unsigned short)(wv.y >> 16));
                const float w4 = bf2f((unsigned short)(wv.z & 0xffffu));
                const float w5 = bf2f((unsigned short)(wv.z >> 16));
                const float w6 = bf2f((unsigned short)(wv.w & 0xffffu));
                const float w7 = bf2f((unsigned short)(wv.w >> 16));
                ax = fmaf(w0, xv0.x, ax); ay = fmaf(w0, yv0.x, ay);
                ax = fmaf(w1, xv0.y, ax); ay = fmaf(w1, yv0.y, ay);
                ax = fmaf(w2, xv0.z, ax); ay = fmaf(w2, yv0.z, ay);
                ax = fmaf(w3, xv0.w, ax); ay = fmaf(w3, yv0.w, ay);
                ax = fmaf(w4, xv1.x, ax); ay = fmaf(w4, yv1.x, ay);
                ax = fmaf(w5, xv1.y, ax); ay = fmaf(w5, yv1.y, ay);
                ax = fmaf(w6, xv1.z, ax); ay = fmaf(w6, yv1.z, ay);
                ax = fmaf(w7, xv1.w, ax); ay = fmaf(w7, yv1.w, ay);
            }
        } else {
            const float4* wr = (const float4*)(W + ((size_t)mid*EE + o)*EE);
            #pragma unroll
            for (int i = 0; i < EE; i += 4) {
                const float4 wv = wr[i >> 2];
                const float4 xv = *(const float4*)&sx[p][cur][i];
                const float4 yv = *(const float4*)&sy[p][cur][i];
                ax = fmaf(wv.x, xv.x, ax); ay = fmaf(wv.x, yv.x, ay);
                ax = fmaf(wv.y, xv.y, ax); ay = fmaf(wv.y, yv.y, ay);
                ax = fmaf(wv.z, xv.z, ax); ay = fmaf(wv.z, yv.z, ay);
                ax = fmaf(wv.w, xv.w, ax); ay = fmaf(wv.w, yv.w, ay);
            }
        }
        sx[p][cur^1][o] = ax;
        sy[p][cur^1][o] = ay;
        __syncthreads();
        cur ^= 1;
    }

    feat[(size_t)bp*(2*EE) + o]      = sx[p][cur][o];
    feat[(size_t)bp*(2*EE) + EE + o] = sy[p][cur][o];
}

// ---------------- fused pooling + full MLP (proven, unchanged) -------------
__global__ __launch_bounds__(256) void k_mlp(
    const int* __restrict__ counts, const float* __restrict__ state,
    const float* __restrict__ W1, const float* __restrict__ b1,
    const float* __restrict__ W2, const float* __restrict__ b2,
    const float* __restrict__ W3, const float* __restrict__ b3,
    float* __restrict__ out)
{
    const int t = threadIdx.x;
    const int b0 = blockIdx.x * 2;
    __shared__ float pl[2][256];
    __shared__ float h1s[2][CC1];
    __shared__ float h2s[2][CC2];
    __shared__ float red[256];

    #pragma unroll
    for (int r = 0; r < 2; ++r) {
        const int b = b0 + r;
        float acc = 0.f, cs = 0.f;
        #pragma unroll
        for (int p = 0; p < PP; ++p) {
            const float cc = (float)counts[b*PP + p];
            cs += cc;
            acc = fmaf(cc, state[((size_t)(b*PP + p))*256 + t], acc);
        }
        pl[r][t] = acc / cs;
    }
    __syncthreads();

    #pragma unroll
    for (int hh = 0; hh < 2; ++hh) {
        const int col = t + hh*256;
        const float4* w4 = (const float4*)(W1 + (size_t)col*256);
        float a0 = b1[col], a1 = a0;
        for (int q = 0; q < 64; ++q) {
            const float4 wv = w4[q];
            const float4 v0 = ((const float4*)pl[0])[q];
            const float4 v1 = ((const float4*)pl[1])[q];
            a0 = fmaf(wv.x,v0.x, fmaf(wv.y,v0.y, fmaf(wv.z,v0.z, fmaf(wv.w,v0.w, a0))));
            a1 = fmaf(wv.x,v1.x, fmaf(wv.y,v1.y, fmaf(wv.z,v1.z, fmaf(wv.w,v1.w, a1))));
        }
        h1s[0][col] = fmaxf(a0, 0.f);
        h1s[1][col] = fmaxf(a1, 0.f);
    }
    __syncthreads();

    {
        const float4* w4 = (const float4*)(W2 + (size_t)t*512);
        float a0 = b2[t], a1 = a0;
        for (int q = 0; q < 128; ++q) {
            const float4 wv = w4[q];
            const float4 v0 = ((const float4*)h1s[0])[q];
            const float4 v1 = ((const float4*)h1s[1])[q];
            a0 = fmaf(wv.x,v0.x, fmaf(wv.y,v0.y, fmaf(wv.z,v0.z, fmaf(wv.w,v0.w, a0))));
            a1 = fmaf(wv.x,v1.x, fmaf(wv.y,v1.y, fmaf(wv.z,v1.z, fmaf(wv.w,v1.w, a1))));
        }
        h2s[0][t] = fmaxf(a0, 0.f);
        h2s[1][t] = fmaxf(a1, 0.f);
    }
    __syncthreads();

    {
        const int r = t >> 7, k = t & 127;
        red[t] = fmaf(W3[k], h2s[r][k], W3[k+128] * h2s[r][k+128]);
        for (int s = 64; s > 0; s >>= 1) {
            __syncthreads();
            if ((t & 127) < s) red[t] += red[t + s];
        }
        __syncthreads();
        if ((t & 127) == 0)
            out[b0 + r] = 1.f / (1.f + expf(-(red[t] + b3[0])));
    }
}

// ---------------------------------------------------------------------------
extern "C" void kernel_launch(void* const* d_in, const int* in_sizes, int n_in,
                              void* d_out, int out_size, void* d_ws, size_t ws_size,
                              hipStream_t stream)
{
    const int*   start_ids  = (const int*)d_in[0];
    const int*   end_ids    = (const int*)d_in[1];
    const int*   module_ids = (const int*)d_in[2];
    const int*   counts     = (const int*)d_in[3];
    const float* embed      = (const float*)d_in[4];
    const float* W          = (const float*)d_in[5];
    const float* bvec       = (const float*)d_in[6];
    const float* W1         = (const float*)d_in[7];
    const float* b1         = (const float*)d_in[8];
    const float* W2         = (const float*)d_in[9];
    const float* b2         = (const float*)d_in[10];
    const float* W3         = (const float*)d_in[11];
    const float* b3         = (const float*)d_in[12];
    float* out  = (float*)d_out;
    char*  ws   = (char*)d_ws;
    float* feat = (float*)(ws + WS_FEAT);

    if (ws_size >= WS_END) {
        unsigned short* Wt = (unsigned short*)(ws + WS_WT);
        // 512*16*128 threads / 256 = 4096 blocks
        k_wtrans<<<4096, 256, 0, stream>>>(W, Wt);
        k_chain<1><<<NPATH/2, 256, 0, stream>>>(start_ids, end_ids, module_ids,
                                                embed, W, Wt, bvec, feat);
    } else {
        k_chain<0><<<NPATH/2, 256, 0, stream>>>(start_ids, end_ids, module_ids,
                                                embed, W, (const unsigned short*)0,
                                                bvec, feat);
    }
    k_mlp<<<BB/2, 256, 0, stream>>>(counts, feat, W1, b1, W2, b2, W3, b3, out);
}